// Round 2
// baseline (440.821 us; speedup 1.0000x reference)
//
#include <hip/hip_runtime.h>
#include <math.h>

// GCN 2-layer forward on MI355X — bucket-partitioned edges + LDS-atomic aggregation.
// R21: kill the CSR sort. The per-node-sorted col array existed only to give
// k_agg/k_l2 contiguous edge runs; instead aggregate straight from the
// bucket-sorted ebuf into an LDS fp32 tile acc[16][128] (bank = dstLocal%32,
// random -> conflict-light ds_add_f32). Removes k_csr's counting sort, col
// (38.4 MB traffic), aggb bf16 round-trip (6.4 MB), rowinfo, and the separate
// k_h launch (dense epilogue fused into k_C on fp32 aggregates).
// Pipeline: k_zero -> k_partition (unchanged) -> k_B (deg/dinv/xsb)
//           -> k_C (agg1 + W1/relu/W2 epilogue -> g2b) -> k_D (agg2 + softmax).

#define NN 100000
#define NE 3200000
#define BSH 7
#define NPB 128                     // nodes per bucket
#define NB  ((NN + NPB - 1) / NPB)  // 782
#define EPB 12544                   // edges per partition block -> 256 blocks
#define CAP 6144                    // slots per bucket region (mean 4096, sigma~64)

// bf16 helpers: value stored in 16 bits; fp32 = bits<<16.
__device__ __forceinline__ float bl(unsigned u) { return __uint_as_float(u << 16); }
__device__ __forceinline__ float bh(unsigned u) { return __uint_as_float(u & 0xFFFF0000u); }
__device__ __forceinline__ unsigned rne(float f) {           // fp32 -> bf16 bits (RNE)
    unsigned u = __float_as_uint(f);
    return (u + 0x7FFFu + ((u >> 16) & 1u)) >> 16;
}

typedef int vint4 __attribute__((ext_vector_type(4)));

// ---------------- kernels ----------------

// Zero the 782 bucket counters (runtime fillBuffer was ~2x slower).
__global__ void __launch_bounds__(256) k_zero(int* __restrict__ bcur) {
    int t = blockIdx.x * 256 + threadIdx.x;
    if (t < NB) bcur[t] = 0;
}

// LDS-staged partition: reg-cached dst (7x int4) -> block hist over 782 buckets
// (two-phase 512-thread scan) -> global reserve (b*CAP + atomicAdd on zeroed
// bcur) -> LDS bucket-sort (sebuf+sbkt) -> coalesced burst copy-out.
// 256 blocks = 1/CU, ~88KB LDS.  (unchanged from R19)
__global__ void __launch_bounds__(512) k_partition(
        const int* __restrict__ src, const int* __restrict__ dst,
        int* __restrict__ bcur, unsigned int* __restrict__ ebuf, int E) {
    __shared__ int hist[NB];
    __shared__ int lbase[NB];
    __shared__ int gbase[NB];
    __shared__ int lcur[NB];
    __shared__ unsigned int sebuf[EPB];
    __shared__ unsigned short sbkt[EPB];
    __shared__ int wsum[8];
    __shared__ int t1_s;
    int tid = threadIdx.x;
    int e0 = blockIdx.x * EPB;
    int e1 = min(e0 + EPB, E);
    int cnt = e1 - e0;                 // multiple of 4 (tail = 1280)
    int cnt4 = cnt >> 2;
    for (int t = tid; t < NB; t += 512) { hist[t] = 0; lcur[t] = 0; }
    __syncthreads();
    const vint4* d4 = (const vint4*)(dst + e0);
    vint4 dc[7];
#pragma unroll
    for (int r = 0; r < 7; r++) {
        int i4 = r * 512 + tid;
        if (i4 < cnt4) {
            dc[r] = d4[i4];
            atomicAdd(&hist[dc[r].x >> BSH], 1);
            atomicAdd(&hist[dc[r].y >> BSH], 1);
            atomicAdd(&hist[dc[r].z >> BSH], 1);
            atomicAdd(&hist[dc[r].w >> BSH], 1);
        }
    }
    __syncthreads();
    int lane = tid & 63, w = tid >> 6;
    // ---- phase 1: scan buckets 0..511 ----
    {
        int v = hist[tid];
        int incl = v;
#pragma unroll
        for (int off = 1; off < 64; off <<= 1) {
            int u = __shfl_up(incl, off);
            if (lane >= off) incl += u;
        }
        if (lane == 63) wsum[w] = incl;
        __syncthreads();
        int woff = 0, tot = 0;
#pragma unroll
        for (int k = 0; k < 8; k++) { tot += wsum[k]; woff += (k < w) ? wsum[k] : 0; }
        int excl = incl - v + woff;
        lbase[tid] = excl;
        gbase[tid] = tid * CAP + (v ? atomicAdd(&bcur[tid], v) : 0);
        if (tid == 0) t1_s = tot;
        __syncthreads();
    }
    // ---- phase 2: scan buckets 512..781 ----
    {
        int b2 = 512 + tid;
        int v = (b2 < NB) ? hist[b2] : 0;
        int incl = v;
#pragma unroll
        for (int off = 1; off < 64; off <<= 1) {
            int u = __shfl_up(incl, off);
            if (lane >= off) incl += u;
        }
        if (lane == 63) wsum[w] = incl;
        __syncthreads();
        int woff = 0;
#pragma unroll
        for (int k = 0; k < 8; k++) woff += (k < w) ? wsum[k] : 0;
        int excl = incl - v + woff + t1_s;
        if (b2 < NB) {
            lbase[b2] = excl;
            gbase[b2] = b2 * CAP + (v ? atomicAdd(&bcur[b2], v) : 0);
        }
        __syncthreads();
    }
    // ---- scatter into LDS, bucket-sorted (dst from regs, src fresh int4) ----
    const vint4* s4 = (const vint4*)(src + e0);
#pragma unroll
    for (int r = 0; r < 7; r++) {
        int i4 = r * 512 + tid;
        if (i4 < cnt4) {
            vint4 sv = s4[i4];
            int d, b, p;
            d = dc[r].x; b = d >> BSH; p = lbase[b] + atomicAdd(&lcur[b], 1);
            sebuf[p] = (unsigned)sv.x | ((unsigned)(d & (NPB - 1)) << 20);
            sbkt[p] = (unsigned short)b;
            d = dc[r].y; b = d >> BSH; p = lbase[b] + atomicAdd(&lcur[b], 1);
            sebuf[p] = (unsigned)sv.y | ((unsigned)(d & (NPB - 1)) << 20);
            sbkt[p] = (unsigned short)b;
            d = dc[r].z; b = d >> BSH; p = lbase[b] + atomicAdd(&lcur[b], 1);
            sebuf[p] = (unsigned)sv.z | ((unsigned)(d & (NPB - 1)) << 20);
            sbkt[p] = (unsigned short)b;
            d = dc[r].w; b = d >> BSH; p = lbase[b] + atomicAdd(&lcur[b], 1);
            sebuf[p] = (unsigned)sv.w | ((unsigned)(d & (NPB - 1)) << 20);
            sbkt[p] = (unsigned short)b;
        }
    }
    __syncthreads();
    // ---- burst copy-out: consecutive lanes -> consecutive ebuf positions ----
    for (int p = tid; p < cnt; p += 512) {
        int b = sbkt[p];
        ebuf[gbase[b] + (p - lbase[b])] = sebuf[p];
    }
}

// Per-bucket degree + dinv + bf16 xs row (x * dinv). One block per bucket.
__global__ void __launch_bounds__(256) k_B(
        const unsigned int* __restrict__ ebuf, const int* __restrict__ bcur,
        const float* __restrict__ x, float* __restrict__ dinv,
        unsigned int* __restrict__ xsb, int N) {
    __shared__ int hist[NPB];
    int b = blockIdx.x, tid = threadIdx.x;
    int beg = b * CAP, cnt = bcur[b];
    if (tid < NPB) hist[tid] = 0;
    __syncthreads();
    for (int j = tid; j < cnt; j += 256)
        atomicAdd(&hist[__builtin_nontemporal_load(&ebuf[beg + j]) >> 20], 1);
    __syncthreads();
    if (tid < NPB) {
        int node = b * NPB + tid;
        if (node < N) {
            int v = hist[tid];
            float di = rsqrtf((float)(v + 1));  // +1 self loop
            dinv[node] = di;
            const float4* x4 = (const float4*)(x + (size_t)node * 16);
            float4 A = x4[0], Bv = x4[1], Cv = x4[2], Dv = x4[3];
            uint4 o0, o1;
            o0.x = rne(A.x * di) | (rne(A.y * di) << 16);
            o0.y = rne(A.z * di) | (rne(A.w * di) << 16);
            o0.z = rne(Bv.x * di) | (rne(Bv.y * di) << 16);
            o0.w = rne(Bv.z * di) | (rne(Bv.w * di) << 16);
            o1.x = rne(Cv.x * di) | (rne(Cv.y * di) << 16);
            o1.y = rne(Cv.z * di) | (rne(Cv.w * di) << 16);
            o1.z = rne(Dv.x * di) | (rne(Dv.y * di) << 16);
            o1.w = rne(Dv.z * di) | (rne(Dv.w * di) << 16);
            uint4* op = (uint4*)xsb;
            op[(size_t)node * 2 + 0] = o0;
            op[(size_t)node * 2 + 1] = o1;
        }
    }
}

// Layer-1 aggregation + dense epilogue, one block per bucket.
// Stream bucket edges from ebuf; per edge gather 32B bf16 xs row and
// ds_add_f32 into acc[feat][dstLocal] (bank = dl%32, random dl -> light
// conflicts). Then tid<128: a = acc + self, h = a@W1, z = relu(di*h+b1),
// p = z@W2, g2b = p*di (bf16x4).
__global__ void __launch_bounds__(256) k_C(
        const unsigned int* __restrict__ ebuf, const int* __restrict__ bcur,
        const unsigned int* __restrict__ xsb, const float* __restrict__ dinv,
        const float* __restrict__ W1, const float* __restrict__ b1,
        const float* __restrict__ W2, unsigned int* __restrict__ g2b, int N) {
    __shared__ float acc[16][NPB];
    __shared__ float W1s[512];
    __shared__ float W2s[96];
    __shared__ float b1s[32];
    int b = blockIdx.x, tid = threadIdx.x;
    int beg = b * CAP, cnt = bcur[b];
    for (int t = tid; t < 512; t += 256) W1s[t] = W1[t];
    if (tid < 96) W2s[tid] = W2[tid];
    if (tid < 32) b1s[tid] = b1[tid];
    float* af = &acc[0][0];
    for (int t = tid; t < 16 * NPB; t += 256) af[t] = 0.f;
    __syncthreads();
    const uint4* xr = (const uint4*)xsb;
    for (int j = tid; j < cnt; j += 256) {
        unsigned pe = __builtin_nontemporal_load(&ebuf[beg + j]);
        int s = (int)(pe & 0xFFFFF), dl = (int)(pe >> 20);
        uint4 q0 = xr[(size_t)s * 2], q1 = xr[(size_t)s * 2 + 1];
        atomicAdd(&acc[0][dl], bl(q0.x));  atomicAdd(&acc[1][dl], bh(q0.x));
        atomicAdd(&acc[2][dl], bl(q0.y));  atomicAdd(&acc[3][dl], bh(q0.y));
        atomicAdd(&acc[4][dl], bl(q0.z));  atomicAdd(&acc[5][dl], bh(q0.z));
        atomicAdd(&acc[6][dl], bl(q0.w));  atomicAdd(&acc[7][dl], bh(q0.w));
        atomicAdd(&acc[8][dl], bl(q1.x));  atomicAdd(&acc[9][dl], bh(q1.x));
        atomicAdd(&acc[10][dl], bl(q1.y)); atomicAdd(&acc[11][dl], bh(q1.y));
        atomicAdd(&acc[12][dl], bl(q1.z)); atomicAdd(&acc[13][dl], bh(q1.z));
        atomicAdd(&acc[14][dl], bl(q1.w)); atomicAdd(&acc[15][dl], bh(q1.w));
    }
    __syncthreads();
    if (tid < NPB) {
        int node = b * NPB + tid;
        if (node < N) {
            float di = dinv[node];
            uint4 s0 = xr[(size_t)node * 2], s1 = xr[(size_t)node * 2 + 1];
            float a[16] = {
                acc[0][tid] + bl(s0.x),  acc[1][tid] + bh(s0.x),
                acc[2][tid] + bl(s0.y),  acc[3][tid] + bh(s0.y),
                acc[4][tid] + bl(s0.z),  acc[5][tid] + bh(s0.z),
                acc[6][tid] + bl(s0.w),  acc[7][tid] + bh(s0.w),
                acc[8][tid] + bl(s1.x),  acc[9][tid] + bh(s1.x),
                acc[10][tid] + bl(s1.y), acc[11][tid] + bh(s1.y),
                acc[12][tid] + bl(s1.z), acc[13][tid] + bh(s1.z),
                acc[14][tid] + bl(s1.w), acc[15][tid] + bh(s1.w)};
            float p0 = 0.f, p1 = 0.f, p2 = 0.f;
#pragma unroll
            for (int jj = 0; jj < 32; jj++) {
                float o = 0.f;
#pragma unroll
                for (int k = 0; k < 16; k++) o = fmaf(a[k], W1s[k * 32 + jj], o);
                float z = fmaxf(fmaf(di, o, b1s[jj]), 0.f);
                p0 = fmaf(z, W2s[jj * 3 + 0], p0);
                p1 = fmaf(z, W2s[jj * 3 + 1], p1);
                p2 = fmaf(z, W2s[jj * 3 + 2], p2);
            }
            uint2 o;
            o.x = rne(p0 * di) | (rne(p1 * di) << 16);
            o.y = rne(p2 * di);
            ((uint2*)g2b)[node] = o;
        }
    }
}

// Layer-2 aggregation + log_softmax, one block per bucket.
// Per edge gather 8B bf16 g2 row, 3x ds_add_f32 into acc[c][dl]; epilogue adds
// self + bias, log_softmax, writes out.
__global__ void __launch_bounds__(256) k_D(
        const unsigned int* __restrict__ ebuf, const int* __restrict__ bcur,
        const unsigned int* __restrict__ g2b, const float* __restrict__ dinv,
        const float* __restrict__ b2, float* __restrict__ out, int N) {
    __shared__ float acc[3][NPB];
    int b = blockIdx.x, tid = threadIdx.x;
    int beg = b * CAP, cnt = bcur[b];
    float* af = &acc[0][0];
    for (int t = tid; t < 3 * NPB; t += 256) af[t] = 0.f;
    __syncthreads();
    const uint2* gb = (const uint2*)g2b;
    for (int j = tid; j < cnt; j += 256) {
        unsigned pe = __builtin_nontemporal_load(&ebuf[beg + j]);
        int s = (int)(pe & 0xFFFFF), dl = (int)(pe >> 20);
        uint2 g = gb[s];
        atomicAdd(&acc[0][dl], bl(g.x));
        atomicAdd(&acc[1][dl], bh(g.x));
        atomicAdd(&acc[2][dl], bl(g.y));
    }
    __syncthreads();
    if (tid < NPB) {
        int node = b * NPB + tid;
        if (node < N) {
            float di = dinv[node];
            uint2 sv = gb[node];
            float v0 = fmaf(di, acc[0][tid] + bl(sv.x), b2[0]);
            float v1 = fmaf(di, acc[1][tid] + bh(sv.x), b2[1]);
            float v2 = fmaf(di, acc[2][tid] + bl(sv.y), b2[2]);
            float m = fmaxf(v0, fmaxf(v1, v2));
            float lse = m + logf(expf(v0 - m) + expf(v1 - m) + expf(v2 - m));
            out[(size_t)node * 3 + 0] = v0 - lse;
            out[(size_t)node * 3 + 1] = v1 - lse;
            out[(size_t)node * 3 + 2] = v2 - lse;
        }
    }
}

// ---------------- launch ----------------

extern "C" void kernel_launch(void* const* d_in, const int* in_sizes, int n_in,
                              void* d_out, int out_size, void* d_ws, size_t ws_size,
                              hipStream_t stream) {
    const float* x  = (const float*)d_in[0];
    const int*   ei = (const int*)d_in[1];   // [2, E] int32
    const float* W1 = (const float*)d_in[2];
    const float* b1 = (const float*)d_in[3];
    const float* W2 = (const float*)d_in[4];
    const float* b2 = (const float*)d_in[5];
    float* out = (float*)d_out;

    const int* src = ei;
    const int* dst = ei + NE;

    // ws (4B units), no aliasing:
    // ebuf[NB*CAP] | xsb[NN*8] | g2b[NN*2] | dinv[NN] | bcur[NB]   (~24 MB)
    unsigned int* ebuf = (unsigned int*)d_ws;
    unsigned int* xsb  = ebuf + (size_t)NB * CAP;
    unsigned int* g2b  = xsb + (size_t)NN * 8;
    float*        dinv = (float*)(g2b + (size_t)NN * 2);
    int*          bcur = (int*)(dinv + NN);

    const int B = 256;
    int gbP = (NE + EPB - 1) / EPB;    // 256
    int gbZ = (NB + B - 1) / B;        // 4

    k_zero<<<gbZ, B, 0, stream>>>(bcur);
    k_partition<<<gbP, 512, 0, stream>>>(src, dst, bcur, ebuf, NE);
    k_B<<<NB, B, 0, stream>>>(ebuf, bcur, x, dinv, xsb, NN);
    k_C<<<NB, B, 0, stream>>>(ebuf, bcur, xsb, dinv, W1, b1, W2, g2b, NN);
    k_D<<<NB, B, 0, stream>>>(ebuf, bcur, g2b, dinv, b2, out, NN);
}

// Round 3
// 98.697 us; speedup vs baseline: 4.4664x; 4.4664x over previous
//
#include <hip/hip_runtime.h>
#include <math.h>

// GCN 2-layer forward on MI355X — fixed-capacity bucket CSR + bf16 gather tables.
// R22: revert R21's LDS-atomic aggregation (k_C was 343us: 16 dependent LDS
// fp32 atomics/edge + 16 serial iters/thread = pure latency stall, VALUBusy 1%).
// Back to the R20 gather/shuffle pipeline, with k_h FUSED into k_agg:
// fold results go to sacc[16][16] LDS (block owns exactly 16 nodes), then the
// W1/relu/W2 epilogue runs on fp32 aggregates (removes the aggb bf16 round-trip
// 6.4MB + one kernel launch). Pipeline: k_zero -> k_partition -> k_csr ->
// k_aggh -> k_l2.

#define NN 100000
#define NE 3200000
#define BSH 7
#define NPB 128                     // nodes per bucket
#define NB  ((NN + NPB - 1) / NPB)  // 782
#define EPB 12544                   // edges per partition block -> 256 blocks
#define CAP 6144                    // slots per bucket region (mean 4096, sigma~64)
#define SCAP 5120                   // LDS staging capacity in k_csr (16 sigma)

// bf16 helpers: value stored in 16 bits; fp32 = bits<<16.
__device__ __forceinline__ float bl(unsigned u) { return __uint_as_float(u << 16); }
__device__ __forceinline__ float bh(unsigned u) { return __uint_as_float(u & 0xFFFF0000u); }
__device__ __forceinline__ unsigned rne(float f) {           // fp32 -> bf16 bits (RNE)
    unsigned u = __float_as_uint(f);
    return (u + 0x7FFFu + ((u >> 16) & 1u)) >> 16;
}

typedef int vint4 __attribute__((ext_vector_type(4)));

// ---------------- kernels ----------------

// Zero the 782 bucket counters (runtime fillBuffer was ~2x slower).
__global__ void __launch_bounds__(256) k_zero(int* __restrict__ bcur) {
    int t = blockIdx.x * 256 + threadIdx.x;
    if (t < NB) bcur[t] = 0;
}

// LDS-staged partition: reg-cached dst (7x int4) -> block hist over 782 buckets
// (two-phase 512-thread scan) -> global reserve (b*CAP + atomicAdd on zeroed
// bcur) -> LDS bucket-sort (sebuf+sbkt) -> coalesced burst copy-out.
// 256 blocks = 1/CU, ~88KB LDS.
__global__ void __launch_bounds__(512) k_partition(
        const int* __restrict__ src, const int* __restrict__ dst,
        int* __restrict__ bcur, unsigned int* __restrict__ ebuf, int E) {
    __shared__ int hist[NB];
    __shared__ int lbase[NB];
    __shared__ int gbase[NB];
    __shared__ int lcur[NB];
    __shared__ unsigned int sebuf[EPB];
    __shared__ unsigned short sbkt[EPB];
    __shared__ int wsum[8];
    __shared__ int t1_s;
    int tid = threadIdx.x;
    int e0 = blockIdx.x * EPB;
    int e1 = min(e0 + EPB, E);
    int cnt = e1 - e0;                 // multiple of 4 (tail = 1280)
    int cnt4 = cnt >> 2;
    for (int t = tid; t < NB; t += 512) { hist[t] = 0; lcur[t] = 0; }
    __syncthreads();
    const vint4* d4 = (const vint4*)(dst + e0);
    vint4 dc[7];
#pragma unroll
    for (int r = 0; r < 7; r++) {
        int i4 = r * 512 + tid;
        if (i4 < cnt4) {
            dc[r] = d4[i4];
            atomicAdd(&hist[dc[r].x >> BSH], 1);
            atomicAdd(&hist[dc[r].y >> BSH], 1);
            atomicAdd(&hist[dc[r].z >> BSH], 1);
            atomicAdd(&hist[dc[r].w >> BSH], 1);
        }
    }
    __syncthreads();
    int lane = tid & 63, w = tid >> 6;
    // ---- phase 1: scan buckets 0..511 ----
    {
        int v = hist[tid];
        int incl = v;
#pragma unroll
        for (int off = 1; off < 64; off <<= 1) {
            int u = __shfl_up(incl, off);
            if (lane >= off) incl += u;
        }
        if (lane == 63) wsum[w] = incl;
        __syncthreads();
        int woff = 0, tot = 0;
#pragma unroll
        for (int k = 0; k < 8; k++) { tot += wsum[k]; woff += (k < w) ? wsum[k] : 0; }
        int excl = incl - v + woff;
        lbase[tid] = excl;
        gbase[tid] = tid * CAP + (v ? atomicAdd(&bcur[tid], v) : 0);
        if (tid == 0) t1_s = tot;
        __syncthreads();
    }
    // ---- phase 2: scan buckets 512..781 ----
    {
        int b2 = 512 + tid;
        int v = (b2 < NB) ? hist[b2] : 0;
        int incl = v;
#pragma unroll
        for (int off = 1; off < 64; off <<= 1) {
            int u = __shfl_up(incl, off);
            if (lane >= off) incl += u;
        }
        if (lane == 63) wsum[w] = incl;
        __syncthreads();
        int woff = 0;
#pragma unroll
        for (int k = 0; k < 8; k++) woff += (k < w) ? wsum[k] : 0;
        int excl = incl - v + woff + t1_s;
        if (b2 < NB) {
            lbase[b2] = excl;
            gbase[b2] = b2 * CAP + (v ? atomicAdd(&bcur[b2], v) : 0);
        }
        __syncthreads();
    }
    // ---- scatter into LDS, bucket-sorted (dst from regs, src fresh int4) ----
    const vint4* s4 = (const vint4*)(src + e0);
#pragma unroll
    for (int r = 0; r < 7; r++) {
        int i4 = r * 512 + tid;
        if (i4 < cnt4) {
            vint4 sv = s4[i4];
            int d, b, p;
            d = dc[r].x; b = d >> BSH; p = lbase[b] + atomicAdd(&lcur[b], 1);
            sebuf[p] = (unsigned)sv.x | ((unsigned)(d & (NPB - 1)) << 20);
            sbkt[p] = (unsigned short)b;
            d = dc[r].y; b = d >> BSH; p = lbase[b] + atomicAdd(&lcur[b], 1);
            sebuf[p] = (unsigned)sv.y | ((unsigned)(d & (NPB - 1)) << 20);
            sbkt[p] = (unsigned short)b;
            d = dc[r].z; b = d >> BSH; p = lbase[b] + atomicAdd(&lcur[b], 1);
            sebuf[p] = (unsigned)sv.z | ((unsigned)(d & (NPB - 1)) << 20);
            sbkt[p] = (unsigned short)b;
            d = dc[r].w; b = d >> BSH; p = lbase[b] + atomicAdd(&lcur[b], 1);
            sebuf[p] = (unsigned)sv.w | ((unsigned)(d & (NPB - 1)) << 20);
            sbkt[p] = (unsigned short)b;
        }
    }
    __syncthreads();
    // ---- burst copy-out: consecutive lanes -> consecutive ebuf positions ----
    for (int p = tid; p < cnt; p += 512) {
        int b = sbkt[p];
        ebuf[gbase[b] + (p - lbase[b])] = sebuf[p];
    }
}

// per-bucket counting sort by dstLocal -> col, bucket staged in LDS (single nt
// ebuf read; scatter from LDS, regular col stores). Emits rowinfo(pos<<8|deg),
// dinv, bf16 xs row. 782 blocks x 256 threads (~3/CU), ~22KB LDS.
__global__ void __launch_bounds__(256) k_csr(
        const unsigned int* __restrict__ ebuf, const int* __restrict__ bcur,
        const float* __restrict__ x, int* __restrict__ col,
        unsigned int* __restrict__ rowinfo, float* __restrict__ dinv,
        unsigned int* __restrict__ xsb, int N) {
    __shared__ unsigned int se[SCAP];
    __shared__ int hist[NPB];
    __shared__ int base[NPB];
    __shared__ int lcur[NPB];
    __shared__ int wsum[4];
    int b = blockIdx.x;
    int tid = threadIdx.x;
    int beg = b * CAP;
    int cnt = bcur[b];               // count (bcur zero-initialized)
    int cl = min(cnt, SCAP);
    if (tid < NPB) { hist[tid] = 0; lcur[tid] = 0; }
    __syncthreads();
    for (int j = tid; j < cl; j += 256) {
        unsigned pe = __builtin_nontemporal_load(&ebuf[beg + j]);
        se[j] = pe;
        atomicAdd(&hist[pe >> 20], 1);
    }
    for (int j = SCAP + tid; j < cnt; j += 256)          // overflow path (~never)
        atomicAdd(&hist[ebuf[beg + j] >> 20], 1);
    __syncthreads();
    int lane = tid & 63, w = tid >> 6;
    int v = (tid < NPB) ? hist[tid] : 0;
    int incl = v;
#pragma unroll
    for (int off = 1; off < 64; off <<= 1) {
        int u = __shfl_up(incl, off);
        if (lane >= off) incl += u;
    }
    if (lane == 63) wsum[w] = incl;
    __syncthreads();
    int woff = 0;
#pragma unroll
    for (int k = 0; k < 4; k++) woff += (k < w) ? wsum[k] : 0;
    int excl = incl - v + woff;
    int node = b * NPB + tid;
    if (tid < NPB) {
        base[tid] = excl;
        if (node < N) {
            float di = rsqrtf((float)(v + 1));  // +1 self loop
            dinv[node] = di;
            rowinfo[node] = ((unsigned)(beg + excl) << 8) | (unsigned)v;  // deg<256
            const float4* x4 = (const float4*)(x + (size_t)node * 16);
            float4 A = x4[0], B = x4[1], C = x4[2], D = x4[3];
            uint4 o0, o1;
            o0.x = rne(A.x * di) | (rne(A.y * di) << 16);
            o0.y = rne(A.z * di) | (rne(A.w * di) << 16);
            o0.z = rne(B.x * di) | (rne(B.y * di) << 16);
            o0.w = rne(B.z * di) | (rne(B.w * di) << 16);
            o1.x = rne(C.x * di) | (rne(C.y * di) << 16);
            o1.y = rne(C.z * di) | (rne(C.w * di) << 16);
            o1.z = rne(D.x * di) | (rne(D.y * di) << 16);
            o1.w = rne(D.z * di) | (rne(D.w * di) << 16);
            uint4* op = (uint4*)xsb;
            op[(size_t)node * 2 + 0] = o0;
            op[(size_t)node * 2 + 1] = o1;
        }
    }
    __syncthreads();
    for (int j = tid; j < cl; j += 256) {
        unsigned pe = se[j];
        int dl = pe >> 20;
        int pos = beg + base[dl] + atomicAdd(&lcur[dl], 1);
        col[pos] = (int)(pe & 0xFFFFF);
    }
    for (int j = SCAP + tid; j < cnt; j += 256) {        // overflow path (~never)
        unsigned pe = ebuf[beg + j];
        int dl = pe >> 20;
        int pos = beg + base[dl] + atomicAdd(&lcur[dl], 1);
        col[pos] = (int)(pe & 0xFFFFF);
    }
}

// Aggregation + fused dense epilogue. FOUR nodes per wave (quarter-wave each),
// 4 edge slots x 4 chunk lanes, uint2 bf16 gathers, unroll x4, 2-level fold,
// + self -> fp32 aggregate in sacc[16][16] (block owns exactly 16 nodes) ->
// h = a@W1, z = relu(di*h+b1), p = z@W2, g2 = p*di (bf16x4), with the 32
// h-columns split 2-per-thread over the node's 16 lanes + shuffle reduce.
// Grid 6250 blocks exactly (NN = 6250*16).
__global__ void __launch_bounds__(256) k_aggh(
        const unsigned int* __restrict__ rowinfo, const int* __restrict__ col,
        const unsigned int* __restrict__ xsb, const float* __restrict__ dinv,
        const float* __restrict__ W1, const float* __restrict__ b1,
        const float* __restrict__ W2, unsigned int* __restrict__ g2b, int N) {
    __shared__ float sacc[16][16];
    __shared__ float W1s[512];
    __shared__ float W2s[96];
    __shared__ float b1s[32];
    int tid = threadIdx.x;
    for (int t = tid; t < 512; t += 256) W1s[t] = W1[t];
    if (tid < 96) W2s[tid] = W2[tid];
    if (tid < 32) b1s[tid] = b1[tid];
    int lane = tid & 63;
    int q = lane >> 4;                 // quarter 0..3 -> node
    int nib = (tid >> 6) * 4 + q;      // node-in-block 0..15
    int wid = blockIdx.x * 16 + nib;
    int lq = lane & 15;
    int r = lq >> 2, c = lq & 3;       // edge slot 0..3, chunk 0..3 (8B)
    const uint2* xb = (const uint2*)xsb;   // row i = xb[i*4 + c]
    if (wid < N) {
        unsigned info = rowinfo[wid];
        int beg = (int)(info >> 8);
        int end = beg + (int)(info & 255u);
        float a0 = 0.f, a1 = 0.f, a2 = 0.f, a3 = 0.f;  // features 4c..4c+3
        int j = beg + r;
        while (j + 12 < end) {   // 4 edges per lane in flight
            int s0 = col[j], s1 = col[j + 4], s2 = col[j + 8], s3 = col[j + 12];
            uint2 q0 = xb[(size_t)s0 * 4 + c];
            uint2 q1 = xb[(size_t)s1 * 4 + c];
            uint2 q2 = xb[(size_t)s2 * 4 + c];
            uint2 q3 = xb[(size_t)s3 * 4 + c];
            a0 += bl(q0.x); a1 += bh(q0.x); a2 += bl(q0.y); a3 += bh(q0.y);
            a0 += bl(q1.x); a1 += bh(q1.x); a2 += bl(q1.y); a3 += bh(q1.y);
            a0 += bl(q2.x); a1 += bh(q2.x); a2 += bl(q2.y); a3 += bh(q2.y);
            a0 += bl(q3.x); a1 += bh(q3.x); a2 += bl(q3.y); a3 += bh(q3.y);
            j += 16;
        }
        while (j < end) {
            int s = col[j];
            uint2 qq = xb[(size_t)s * 4 + c];
            a0 += bl(qq.x); a1 += bh(qq.x); a2 += bl(qq.y); a3 += bh(qq.y);
            j += 4;
        }
        // fold 4 edge slots -> lanes lq 0..3 of each quarter (chunk c preserved)
#pragma unroll
        for (int off = 8; off >= 4; off >>= 1) {
            a0 += __shfl_down(a0, off);
            a1 += __shfl_down(a1, off);
            a2 += __shfl_down(a2, off);
            a3 += __shfl_down(a3, off);
        }
        if (lq < 4) {  // self term + stash fp32 aggregate (chunk c == lq)
            uint2 qq = xb[(size_t)wid * 4 + lq];
            sacc[nib][lq * 4 + 0] = a0 + bl(qq.x);
            sacc[nib][lq * 4 + 1] = a1 + bh(qq.x);
            sacc[nib][lq * 4 + 2] = a2 + bl(qq.y);
            sacc[nib][lq * 4 + 3] = a3 + bh(qq.y);
        }
    }
    __syncthreads();
    // ---- dense epilogue: thread t -> (node t>>4, h-cols t&15 and (t&15)+16)
    int nib2 = tid >> 4, j16 = tid & 15;
    int node = blockIdx.x * 16 + nib2;
    float p0 = 0.f, p1 = 0.f, p2 = 0.f, di = 0.f;
    if (node < N) {
        di = dinv[node];
        float h0 = 0.f, h1 = 0.f;
#pragma unroll
        for (int k = 0; k < 16; k++) {
            float ak = sacc[nib2][k];      // broadcast within node's 16 lanes
            h0 = fmaf(ak, W1s[k * 32 + j16], h0);
            h1 = fmaf(ak, W1s[k * 32 + j16 + 16], h1);
        }
        float z0 = fmaxf(fmaf(di, h0, b1s[j16]), 0.f);
        float z1 = fmaxf(fmaf(di, h1, b1s[j16 + 16]), 0.f);
        p0 = fmaf(z1, W2s[(j16 + 16) * 3 + 0], z0 * W2s[j16 * 3 + 0]);
        p1 = fmaf(z1, W2s[(j16 + 16) * 3 + 1], z0 * W2s[j16 * 3 + 1]);
        p2 = fmaf(z1, W2s[(j16 + 16) * 3 + 2], z0 * W2s[j16 * 3 + 2]);
    }
#pragma unroll
    for (int off = 8; off >= 1; off >>= 1) {
        p0 += __shfl_down(p0, off);
        p1 += __shfl_down(p1, off);
        p2 += __shfl_down(p2, off);
    }
    if (j16 == 0 && node < N) {
        uint2 o;
        o.x = rne(p0 * di) | (rne(p1 * di) << 16);
        o.y = rne(p2 * di);
        ((uint2*)g2b)[node] = o;
    }
}

// Layer-2: EIGHT nodes per wave (8 lanes each), 8B bf16 g2 gathers, unroll x2,
// 3-level shuffle reduce, + self + bias, log_softmax.
__global__ void __launch_bounds__(256) k_l2(
        const unsigned int* __restrict__ rowinfo, const int* __restrict__ col,
        const unsigned int* __restrict__ g2b, const float* __restrict__ dinv,
        const float* __restrict__ b2, float* __restrict__ out, int N) {
    int wid = (int)((blockIdx.x * 256 + threadIdx.x) >> 3);  // node per 8 lanes
    if (wid >= N) return;
    int lo = threadIdx.x & 7;
    unsigned info = rowinfo[wid];
    int beg = (int)(info >> 8);
    int end = beg + (int)(info & 255u);
    const uint2* gb = (const uint2*)g2b;
    float a0 = 0.f, a1 = 0.f, a2 = 0.f;
    int j = beg + lo;
    while (j + 8 < end) {   // 2 edges in flight
        uint2 v0 = gb[col[j]];
        uint2 v1 = gb[col[j + 8]];
        a0 += bl(v0.x); a1 += bh(v0.x); a2 += bl(v0.y);
        a0 += bl(v1.x); a1 += bh(v1.x); a2 += bl(v1.y);
        j += 16;
    }
    if (j < end) {
        uint2 v = gb[col[j]];
        a0 += bl(v.x); a1 += bh(v.x); a2 += bl(v.y);
    }
#pragma unroll
    for (int off = 4; off >= 1; off >>= 1) {
        a0 += __shfl_down(a0, off);
        a1 += __shfl_down(a1, off);
        a2 += __shfl_down(a2, off);
    }
    if (lo == 0) {
        float di = dinv[wid];
        uint2 sv = gb[wid];
        float v0 = fmaf(di, a0 + bl(sv.x), b2[0]);
        float v1 = fmaf(di, a1 + bh(sv.x), b2[1]);
        float v2 = fmaf(di, a2 + bl(sv.y), b2[2]);
        float m = fmaxf(v0, fmaxf(v1, v2));
        float lse = m + logf(expf(v0 - m) + expf(v1 - m) + expf(v2 - m));
        out[(size_t)wid * 3 + 0] = v0 - lse;
        out[(size_t)wid * 3 + 1] = v1 - lse;
        out[(size_t)wid * 3 + 2] = v2 - lse;
    }
}

// ---------------- launch ----------------

extern "C" void kernel_launch(void* const* d_in, const int* in_sizes, int n_in,
                              void* d_out, int out_size, void* d_ws, size_t ws_size,
                              hipStream_t stream) {
    const float* x  = (const float*)d_in[0];
    const int*   ei = (const int*)d_in[1];   // [2, E] int32
    const float* W1 = (const float*)d_in[2];
    const float* b1 = (const float*)d_in[3];
    const float* W2 = (const float*)d_in[4];
    const float* b2 = (const float*)d_in[5];
    float* out = (float*)d_out;

    const int* src = ei;
    const int* dst = ei + NE;

    // ws (4B units), no aliasing:
    // ebuf[NB*CAP] | col[NB*CAP] | xsb[NN*8] | g2b[NN*2]
    // | dinv[NN] | rowinfo[NN] | bcur[NB]        (~48 MB)
    unsigned int* ebuf = (unsigned int*)d_ws;
    int*          col  = (int*)(ebuf + (size_t)NB * CAP);
    unsigned int* xsb  = (unsigned int*)(col + (size_t)NB * CAP);
    unsigned int* g2b  = xsb + (size_t)NN * 8;
    float*        dinv = (float*)(g2b + (size_t)NN * 2);
    unsigned int* rowinfo = (unsigned int*)(dinv + NN);
    int*          bcur = (int*)(rowinfo + NN);

    const int B = 256;
    int gbP = (NE + EPB - 1) / EPB;    // 256
    int gbW1 = (NN * 16 + B - 1) / B;  // 6250, quarter-wave per node
    int gbW2 = (NN * 8 + B - 1) / B;   // 8 lanes per node
    int gbZ = (NB + B - 1) / B;        // 4

    k_zero<<<gbZ, B, 0, stream>>>(bcur);
    k_partition<<<gbP, 512, 0, stream>>>(src, dst, bcur, ebuf, NE);
    k_csr<<<NB, B, 0, stream>>>(ebuf, bcur, x, col, rowinfo, dinv, xsb, NN);
    k_aggh<<<gbW1, B, 0, stream>>>(rowinfo, col, xsb, dinv, W1, b1, W2, g2b, NN);
    k_l2<<<gbW2, B, 0, stream>>>(rowinfo, col, g2b, dinv, b2, out, NN);
}

// Round 4
// 95.283 us; speedup vs baseline: 4.6264x; 1.0358x over previous
//
#include <hip/hip_runtime.h>
#include <math.h>

// GCN 2-layer forward on MI355X — fixed-capacity bucket CSR + bf16 gather tables.
// R23: revert R22's epilogue fusion (regressed 96.6->98.7: extra sync+reduce in
// the hot kernel cost more than the saved launch+roundtrip). Back to R20's
// 6-kernel pipeline, with k_agg restructured: 8 edge-slots x 2 chunk-lanes,
// uint4 (16B) gathers — same bytes, HALF the VMEM requests per edge, same 16
// edges in flight per wave. Pipeline: k_zero -> k_partition -> k_csr -> k_agg
// -> k_h -> k_l2.

#define NN 100000
#define NE 3200000
#define BSH 7
#define NPB 128                     // nodes per bucket
#define NB  ((NN + NPB - 1) / NPB)  // 782
#define EPB 12544                   // edges per partition block -> 256 blocks
#define CAP 6144                    // slots per bucket region (mean 4096, sigma~64)
#define SCAP 5120                   // LDS staging capacity in k_csr (16 sigma)

// bf16 helpers: value stored in 16 bits; fp32 = bits<<16.
__device__ __forceinline__ float bl(unsigned u) { return __uint_as_float(u << 16); }
__device__ __forceinline__ float bh(unsigned u) { return __uint_as_float(u & 0xFFFF0000u); }
__device__ __forceinline__ unsigned rne(float f) {           // fp32 -> bf16 bits (RNE)
    unsigned u = __float_as_uint(f);
    return (u + 0x7FFFu + ((u >> 16) & 1u)) >> 16;
}

typedef int vint4 __attribute__((ext_vector_type(4)));

// ---------------- kernels ----------------

// Zero the 782 bucket counters (runtime fillBuffer was ~2x slower).
__global__ void __launch_bounds__(256) k_zero(int* __restrict__ bcur) {
    int t = blockIdx.x * 256 + threadIdx.x;
    if (t < NB) bcur[t] = 0;
}

// LDS-staged partition: reg-cached dst (7x int4) -> block hist over 782 buckets
// (two-phase 512-thread scan) -> global reserve (b*CAP + atomicAdd on zeroed
// bcur) -> LDS bucket-sort (sebuf+sbkt) -> coalesced burst copy-out.
// 256 blocks = 1/CU, ~88KB LDS.
__global__ void __launch_bounds__(512) k_partition(
        const int* __restrict__ src, const int* __restrict__ dst,
        int* __restrict__ bcur, unsigned int* __restrict__ ebuf, int E) {
    __shared__ int hist[NB];
    __shared__ int lbase[NB];
    __shared__ int gbase[NB];
    __shared__ int lcur[NB];
    __shared__ unsigned int sebuf[EPB];
    __shared__ unsigned short sbkt[EPB];
    __shared__ int wsum[8];
    __shared__ int t1_s;
    int tid = threadIdx.x;
    int e0 = blockIdx.x * EPB;
    int e1 = min(e0 + EPB, E);
    int cnt = e1 - e0;                 // multiple of 4 (tail = 1280)
    int cnt4 = cnt >> 2;
    for (int t = tid; t < NB; t += 512) { hist[t] = 0; lcur[t] = 0; }
    __syncthreads();
    const vint4* d4 = (const vint4*)(dst + e0);
    vint4 dc[7];
#pragma unroll
    for (int r = 0; r < 7; r++) {
        int i4 = r * 512 + tid;
        if (i4 < cnt4) {
            dc[r] = d4[i4];
            atomicAdd(&hist[dc[r].x >> BSH], 1);
            atomicAdd(&hist[dc[r].y >> BSH], 1);
            atomicAdd(&hist[dc[r].z >> BSH], 1);
            atomicAdd(&hist[dc[r].w >> BSH], 1);
        }
    }
    __syncthreads();
    int lane = tid & 63, w = tid >> 6;
    // ---- phase 1: scan buckets 0..511 ----
    {
        int v = hist[tid];
        int incl = v;
#pragma unroll
        for (int off = 1; off < 64; off <<= 1) {
            int u = __shfl_up(incl, off);
            if (lane >= off) incl += u;
        }
        if (lane == 63) wsum[w] = incl;
        __syncthreads();
        int woff = 0, tot = 0;
#pragma unroll
        for (int k = 0; k < 8; k++) { tot += wsum[k]; woff += (k < w) ? wsum[k] : 0; }
        int excl = incl - v + woff;
        lbase[tid] = excl;
        gbase[tid] = tid * CAP + (v ? atomicAdd(&bcur[tid], v) : 0);
        if (tid == 0) t1_s = tot;
        __syncthreads();
    }
    // ---- phase 2: scan buckets 512..781 ----
    {
        int b2 = 512 + tid;
        int v = (b2 < NB) ? hist[b2] : 0;
        int incl = v;
#pragma unroll
        for (int off = 1; off < 64; off <<= 1) {
            int u = __shfl_up(incl, off);
            if (lane >= off) incl += u;
        }
        if (lane == 63) wsum[w] = incl;
        __syncthreads();
        int woff = 0;
#pragma unroll
        for (int k = 0; k < 8; k++) woff += (k < w) ? wsum[k] : 0;
        int excl = incl - v + woff + t1_s;
        if (b2 < NB) {
            lbase[b2] = excl;
            gbase[b2] = b2 * CAP + (v ? atomicAdd(&bcur[b2], v) : 0);
        }
        __syncthreads();
    }
    // ---- scatter into LDS, bucket-sorted (dst from regs, src fresh int4) ----
    const vint4* s4 = (const vint4*)(src + e0);
#pragma unroll
    for (int r = 0; r < 7; r++) {
        int i4 = r * 512 + tid;
        if (i4 < cnt4) {
            vint4 sv = s4[i4];
            int d, b, p;
            d = dc[r].x; b = d >> BSH; p = lbase[b] + atomicAdd(&lcur[b], 1);
            sebuf[p] = (unsigned)sv.x | ((unsigned)(d & (NPB - 1)) << 20);
            sbkt[p] = (unsigned short)b;
            d = dc[r].y; b = d >> BSH; p = lbase[b] + atomicAdd(&lcur[b], 1);
            sebuf[p] = (unsigned)sv.y | ((unsigned)(d & (NPB - 1)) << 20);
            sbkt[p] = (unsigned short)b;
            d = dc[r].z; b = d >> BSH; p = lbase[b] + atomicAdd(&lcur[b], 1);
            sebuf[p] = (unsigned)sv.z | ((unsigned)(d & (NPB - 1)) << 20);
            sbkt[p] = (unsigned short)b;
            d = dc[r].w; b = d >> BSH; p = lbase[b] + atomicAdd(&lcur[b], 1);
            sebuf[p] = (unsigned)sv.w | ((unsigned)(d & (NPB - 1)) << 20);
            sbkt[p] = (unsigned short)b;
        }
    }
    __syncthreads();
    // ---- burst copy-out: consecutive lanes -> consecutive ebuf positions ----
    for (int p = tid; p < cnt; p += 512) {
        int b = sbkt[p];
        ebuf[gbase[b] + (p - lbase[b])] = sebuf[p];
    }
}

// per-bucket counting sort by dstLocal -> col, bucket staged in LDS (single nt
// ebuf read; scatter from LDS, regular col stores). Emits rowinfo(pos<<8|deg),
// dinv, bf16 xs row. 782 blocks x 256 threads (~3/CU), ~22KB LDS.
__global__ void __launch_bounds__(256) k_csr(
        const unsigned int* __restrict__ ebuf, const int* __restrict__ bcur,
        const float* __restrict__ x, int* __restrict__ col,
        unsigned int* __restrict__ rowinfo, float* __restrict__ dinv,
        unsigned int* __restrict__ xsb, int N) {
    __shared__ unsigned int se[SCAP];
    __shared__ int hist[NPB];
    __shared__ int base[NPB];
    __shared__ int lcur[NPB];
    __shared__ int wsum[4];
    int b = blockIdx.x;
    int tid = threadIdx.x;
    int beg = b * CAP;
    int cnt = bcur[b];               // count (bcur zero-initialized)
    int cl = min(cnt, SCAP);
    if (tid < NPB) { hist[tid] = 0; lcur[tid] = 0; }
    __syncthreads();
    for (int j = tid; j < cl; j += 256) {
        unsigned pe = __builtin_nontemporal_load(&ebuf[beg + j]);
        se[j] = pe;
        atomicAdd(&hist[pe >> 20], 1);
    }
    for (int j = SCAP + tid; j < cnt; j += 256)          // overflow path (~never)
        atomicAdd(&hist[ebuf[beg + j] >> 20], 1);
    __syncthreads();
    int lane = tid & 63, w = tid >> 6;
    int v = (tid < NPB) ? hist[tid] : 0;
    int incl = v;
#pragma unroll
    for (int off = 1; off < 64; off <<= 1) {
        int u = __shfl_up(incl, off);
        if (lane >= off) incl += u;
    }
    if (lane == 63) wsum[w] = incl;
    __syncthreads();
    int woff = 0;
#pragma unroll
    for (int k = 0; k < 4; k++) woff += (k < w) ? wsum[k] : 0;
    int excl = incl - v + woff;
    int node = b * NPB + tid;
    if (tid < NPB) {
        base[tid] = excl;
        if (node < N) {
            float di = rsqrtf((float)(v + 1));  // +1 self loop
            dinv[node] = di;
            rowinfo[node] = ((unsigned)(beg + excl) << 8) | (unsigned)v;  // deg<256
            const float4* x4 = (const float4*)(x + (size_t)node * 16);
            float4 A = x4[0], B = x4[1], C = x4[2], D = x4[3];
            uint4 o0, o1;
            o0.x = rne(A.x * di) | (rne(A.y * di) << 16);
            o0.y = rne(A.z * di) | (rne(A.w * di) << 16);
            o0.z = rne(B.x * di) | (rne(B.y * di) << 16);
            o0.w = rne(B.z * di) | (rne(B.w * di) << 16);
            o1.x = rne(C.x * di) | (rne(C.y * di) << 16);
            o1.y = rne(C.z * di) | (rne(C.w * di) << 16);
            o1.z = rne(D.x * di) | (rne(D.y * di) << 16);
            o1.w = rne(D.z * di) | (rne(D.w * di) << 16);
            uint4* op = (uint4*)xsb;
            op[(size_t)node * 2 + 0] = o0;
            op[(size_t)node * 2 + 1] = o1;
        }
    }
    __syncthreads();
    for (int j = tid; j < cl; j += 256) {
        unsigned pe = se[j];
        int dl = pe >> 20;
        int pos = beg + base[dl] + atomicAdd(&lcur[dl], 1);
        col[pos] = (int)(pe & 0xFFFFF);
    }
    for (int j = SCAP + tid; j < cnt; j += 256) {        // overflow path (~never)
        unsigned pe = ebuf[beg + j];
        int dl = pe >> 20;
        int pos = beg + base[dl] + atomicAdd(&lcur[dl], 1);
        col[pos] = (int)(pe & 0xFFFFF);
    }
}

// Aggregation: FOUR nodes per wave (quarter-wave each), 8 edge slots x 2 chunk
// lanes, uint4 (16B) bf16 gathers — half the VMEM requests of the 4x4/uint2
// shape, same 16 edges in flight. 3-level fold, + self, write agg16 row bf16.
__global__ void __launch_bounds__(256) k_agg(
        const unsigned int* __restrict__ rowinfo, const int* __restrict__ col,
        const unsigned int* __restrict__ xsb, unsigned int* __restrict__ aggb,
        int N) {
    int wv = (int)((blockIdx.x * 256 + threadIdx.x) >> 6);
    int lane = threadIdx.x & 63;
    int q = lane >> 4;                 // quarter 0..3 -> node
    int wid = wv * 4 + q;
    if (wid >= N) return;              // quarter-wave-uniform
    int lq = lane & 15;
    int r = lq >> 1, c = lq & 1;       // edge slot 0..7, chunk 0..1 (16B)
    unsigned info = rowinfo[wid];
    int beg = (int)(info >> 8);
    int end = beg + (int)(info & 255u);
    const uint4* xb = (const uint4*)xsb;   // row i = xb[i*2 + c]
    float a0 = 0.f, a1 = 0.f, a2 = 0.f, a3 = 0.f;   // features 8c..8c+7
    float a4 = 0.f, a5 = 0.f, a6 = 0.f, a7 = 0.f;
    int j = beg + r;
    while (j + 8 < end) {   // 2 edges per lane in flight (16/wave-quarter)
        int s0 = col[j], s1 = col[j + 8];
        uint4 q0 = xb[(size_t)s0 * 2 + c];
        uint4 q1 = xb[(size_t)s1 * 2 + c];
        a0 += bl(q0.x); a1 += bh(q0.x); a2 += bl(q0.y); a3 += bh(q0.y);
        a4 += bl(q0.z); a5 += bh(q0.z); a6 += bl(q0.w); a7 += bh(q0.w);
        a0 += bl(q1.x); a1 += bh(q1.x); a2 += bl(q1.y); a3 += bh(q1.y);
        a4 += bl(q1.z); a5 += bh(q1.z); a6 += bl(q1.w); a7 += bh(q1.w);
        j += 16;
    }
    if (j < end) {
        int s = col[j];
        uint4 qq = xb[(size_t)s * 2 + c];
        a0 += bl(qq.x); a1 += bh(qq.x); a2 += bl(qq.y); a3 += bh(qq.y);
        a4 += bl(qq.z); a5 += bh(qq.z); a6 += bl(qq.w); a7 += bh(qq.w);
    }
    // fold 8 edge slots -> lanes lq 0..1 of each quarter (chunk c preserved)
#pragma unroll
    for (int off = 8; off >= 2; off >>= 1) {
        a0 += __shfl_down(a0, off);
        a1 += __shfl_down(a1, off);
        a2 += __shfl_down(a2, off);
        a3 += __shfl_down(a3, off);
        a4 += __shfl_down(a4, off);
        a5 += __shfl_down(a5, off);
        a6 += __shfl_down(a6, off);
        a7 += __shfl_down(a7, off);
    }
    if (lq < 2) {  // self term + write (chunk c == lq)
        uint4 qq = xb[(size_t)wid * 2 + lq];
        a0 += bl(qq.x); a1 += bh(qq.x); a2 += bl(qq.y); a3 += bh(qq.y);
        a4 += bl(qq.z); a5 += bh(qq.z); a6 += bl(qq.w); a7 += bh(qq.w);
        uint4 o;
        o.x = rne(a0) | (rne(a1) << 16);
        o.y = rne(a2) | (rne(a3) << 16);
        o.z = rne(a4) | (rne(a5) << 16);
        o.w = rne(a6) | (rne(a7) << 16);
        ((uint4*)aggb)[(size_t)wid * 2 + lq] = o;
    }
}

// Dense per-node epilogue: h = agg16 @ W1, z = relu(dinv*h + b1),
// p = z @ W2, g2 = p*dinv (bf16x4). One thread per node, zero shuffles.
__global__ void __launch_bounds__(256) k_h(
        const unsigned int* __restrict__ aggb, const float* __restrict__ dinv,
        const float* __restrict__ W1, const float* __restrict__ b1,
        const float* __restrict__ W2, unsigned int* __restrict__ g2b, int N) {
    __shared__ float W1s[16 * 32];
    __shared__ float W2s[96];
    __shared__ float b1s[32];
    for (int t = threadIdx.x; t < 512; t += 256) W1s[t] = W1[t];
    if (threadIdx.x < 96) W2s[threadIdx.x] = W2[threadIdx.x];
    if (threadIdx.x < 32) b1s[threadIdx.x] = b1[threadIdx.x];
    __syncthreads();
    int i = blockIdx.x * 256 + threadIdx.x;
    if (i >= N) return;
    const uint4* ab = (const uint4*)aggb;
    uint4 q0 = ab[(size_t)i * 2 + 0];
    uint4 q1 = ab[(size_t)i * 2 + 1];
    float a[16] = {bl(q0.x), bh(q0.x), bl(q0.y), bh(q0.y),
                   bl(q0.z), bh(q0.z), bl(q0.w), bh(q0.w),
                   bl(q1.x), bh(q1.x), bl(q1.y), bh(q1.y),
                   bl(q1.z), bh(q1.z), bl(q1.w), bh(q1.w)};
    float di = dinv[i];
    float p0 = 0.f, p1 = 0.f, p2 = 0.f;
#pragma unroll
    for (int jj = 0; jj < 32; jj++) {
        float o = 0.f;
#pragma unroll
        for (int k = 0; k < 16; k++) o = fmaf(a[k], W1s[k * 32 + jj], o);
        float z = fmaxf(fmaf(di, o, b1s[jj]), 0.f);
        p0 = fmaf(z, W2s[jj * 3 + 0], p0);
        p1 = fmaf(z, W2s[jj * 3 + 1], p1);
        p2 = fmaf(z, W2s[jj * 3 + 2], p2);
    }
    uint2 o;
    o.x = rne(p0 * di) | (rne(p1 * di) << 16);
    o.y = rne(p2 * di);
    ((uint2*)g2b)[i] = o;
}

// Layer-2: EIGHT nodes per wave (8 lanes each), 8B bf16 g2 gathers, unroll x2,
// 3-level shuffle reduce, + self + bias, log_softmax.
__global__ void __launch_bounds__(256) k_l2(
        const unsigned int* __restrict__ rowinfo, const int* __restrict__ col,
        const unsigned int* __restrict__ g2b, const float* __restrict__ dinv,
        const float* __restrict__ b2, float* __restrict__ out, int N) {
    int wid = (int)((blockIdx.x * 256 + threadIdx.x) >> 3);  // node per 8 lanes
    if (wid >= N) return;
    int lo = threadIdx.x & 7;
    unsigned info = rowinfo[wid];
    int beg = (int)(info >> 8);
    int end = beg + (int)(info & 255u);
    const uint2* gb = (const uint2*)g2b;
    float a0 = 0.f, a1 = 0.f, a2 = 0.f;
    int j = beg + lo;
    while (j + 8 < end) {   // 2 edges in flight
        uint2 v0 = gb[col[j]];
        uint2 v1 = gb[col[j + 8]];
        a0 += bl(v0.x); a1 += bh(v0.x); a2 += bl(v0.y);
        a0 += bl(v1.x); a1 += bh(v1.x); a2 += bl(v1.y);
        j += 16;
    }
    if (j < end) {
        uint2 v = gb[col[j]];
        a0 += bl(v.x); a1 += bh(v.x); a2 += bl(v.y);
    }
#pragma unroll
    for (int off = 4; off >= 1; off >>= 1) {
        a0 += __shfl_down(a0, off);
        a1 += __shfl_down(a1, off);
        a2 += __shfl_down(a2, off);
    }
    if (lo == 0) {
        float di = dinv[wid];
        uint2 sv = gb[wid];
        float v0 = fmaf(di, a0 + bl(sv.x), b2[0]);
        float v1 = fmaf(di, a1 + bh(sv.x), b2[1]);
        float v2 = fmaf(di, a2 + bl(sv.y), b2[2]);
        float m = fmaxf(v0, fmaxf(v1, v2));
        float lse = m + logf(expf(v0 - m) + expf(v1 - m) + expf(v2 - m));
        out[(size_t)wid * 3 + 0] = v0 - lse;
        out[(size_t)wid * 3 + 1] = v1 - lse;
        out[(size_t)wid * 3 + 2] = v2 - lse;
    }
}

// ---------------- launch ----------------

extern "C" void kernel_launch(void* const* d_in, const int* in_sizes, int n_in,
                              void* d_out, int out_size, void* d_ws, size_t ws_size,
                              hipStream_t stream) {
    const float* x  = (const float*)d_in[0];
    const int*   ei = (const int*)d_in[1];   // [2, E] int32
    const float* W1 = (const float*)d_in[2];
    const float* b1 = (const float*)d_in[3];
    const float* W2 = (const float*)d_in[4];
    const float* b2 = (const float*)d_in[5];
    float* out = (float*)d_out;

    const int* src = ei;
    const int* dst = ei + NE;

    // ws (4B units), no aliasing:
    // ebuf[NB*CAP] | col[NB*CAP] | xsb[NN*8] | aggb[NN*8] | g2b[NN*2]
    // | dinv[NN] | rowinfo[NN] | bcur[NB]        (~55 MB)
    unsigned int* ebuf = (unsigned int*)d_ws;
    int*          col  = (int*)(ebuf + (size_t)NB * CAP);
    unsigned int* xsb  = (unsigned int*)(col + (size_t)NB * CAP);
    unsigned int* aggb = xsb + (size_t)NN * 8;
    unsigned int* g2b  = aggb + (size_t)NN * 8;
    float*        dinv = (float*)(g2b + (size_t)NN * 2);
    unsigned int* rowinfo = (unsigned int*)(dinv + NN);
    int*          bcur = (int*)(rowinfo + NN);

    const int B = 256;
    int gbP = (NE + EPB - 1) / EPB;    // 256
    int gbS = (NN + B - 1) / B;
    int gbW1 = (NN * 16 + B - 1) / B;  // quarter-wave per node
    int gbW2 = (NN * 8 + B - 1) / B;   // 8 lanes per node
    int gbZ = (NB + B - 1) / B;        // 4

    k_zero<<<gbZ, B, 0, stream>>>(bcur);
    k_partition<<<gbP, 512, 0, stream>>>(src, dst, bcur, ebuf, NE);
    k_csr<<<NB, B, 0, stream>>>(ebuf, bcur, x, col, rowinfo, dinv, xsb, NN);
    k_agg<<<gbW1, B, 0, stream>>>(rowinfo, col, xsb, aggb, NN);
    k_h<<<gbS, B, 0, stream>>>(aggb, dinv, W1, b1, W2, g2b, NN);
    k_l2<<<gbW2, B, 0, stream>>>(rowinfo, col, g2b, dinv, b2, out, NN);
}